// Round 6
// baseline (598.485 us; speedup 1.0000x reference)
//
#include <hip/hip_runtime.h>
#include <math.h>

#define BB 1024
#define LL 256
#define VV 50000
#define EE 300
#define AA 30
#define RPT 6                      // vocab rows per thread
#define ROWS_PER_BLOCK 48          // 8 slots * RPT
#define WORD_THRES 0.2f
#define COS_EPS_F 1e-8f
#define NEG_INF_F -1e9f

// ---------------------------------------------------------------------------
// Kernel 1: cent[v] = max_a ( (cos(a_emb[a], w_emb[v]) > thres ? cos : 0) * w[a] )
// Aspect-split ACROSS waves: wave w owns aspects {0-7, 8-15, 16-22, 23-29};
// all 4 waves process the same 48 rows (lane = 8 E-lanes x 8 row-slots,
// 6 rows/thread). Inner ds_read_b128 is single-aspect -> 8 distinct addrs
// tile banks 4p..4p+3 exactly: zero conflicts. Branch-free 9-iter K-loop +
// exec-masked tail. LDS 36.6 KB + VGPR<=128 -> 4 blocks/CU; grid 1042.
// ---------------------------------------------------------------------------
__global__ void __launch_bounds__(256, 4) cent_kernel(
    const float* __restrict__ w_emb,     // [V, E]
    const float* __restrict__ a_emb,     // [A, E]
    const float* __restrict__ a_weight,  // [A]
    float* __restrict__ cent)            // [V]
{
    __shared__ float4 s_a[AA * 75];      // a-major: s_a[a*75 + j], 36000 B
    __shared__ float s_scale[AA];        // 1 / max(||a||, eps)
    __shared__ float s_aw[AA];
    __shared__ float s_pm[ROWS_PER_BLOCK * 4];  // per-row partial max per wave

    const int t = threadIdx.x;
    const int lane = t & 63;
    const int w = t >> 6;            // wave id 0..3
    const int p = lane & 7;          // E-lane: float4 col j = 8k + p
    const int s = lane >> 3;         // row slot 0..7

    const float4* __restrict__ a4 = (const float4*)a_emb;   // [A][75]

    // stage a_emb -> LDS (coalesced copy)
    for (int i = t; i < AA * 75; i += 256) s_a[i] = a4[i];

    // aspect norms: 8 lanes per aspect (in-wave groups, threads 0..239)
    {
        const int a = t >> 3, j = t & 7;
        if (a < AA) {
            float n2a = 0.f;
            for (int c = j; c < 75; c += 8) {
                const float4 x = a4[a * 75 + c];
                n2a += x.x * x.x + x.y * x.y + x.z * x.z + x.w * x.w;
            }
            n2a += __shfl_xor(n2a, 1);
            n2a += __shfl_xor(n2a, 2);
            n2a += __shfl_xor(n2a, 4);
            if (j == 0) {
                s_scale[a] = 1.f / fmaxf(sqrtf(n2a), COS_EPS_F);
                s_aw[a] = a_weight[a];
            }
        }
    }
    __syncthreads();

    // wave's aspect range: 8,8,7,7 -> bases 0,8,16,23
    const int abase = (w < 3) ? w * 8 : 23;
    const int cw    = (w < 2) ? 8 : 7;
    int ai[8];
#pragma unroll
    for (int a = 0; a < 8; ++a) ai[a] = abase + ((a < cw) ? a : cw - 1);

    // row pointers (clamped for tail block), pre-offset by this lane's p
    const int vbase = blockIdx.x * ROWS_PER_BLOCK + s * RPT;
    const float* __restrict__ rp[RPT];
#pragma unroll
    for (int i = 0; i < RPT; ++i) {
        const int v = vbase + i;
        rp[i] = w_emb + (size_t)((v < VV) ? v : 0) * EE + 4 * p;
    }

    float acc[8][RPT];
#pragma unroll
    for (int a = 0; a < 8; ++a)
#pragma unroll
        for (int i = 0; i < RPT; ++i) acc[a][i] = 0.f;
    float n2[RPT] = {0.f, 0.f, 0.f, 0.f, 0.f, 0.f};

    // main loop: k = 0..8, col j = 8k+p <= 71, branch-free
#pragma unroll
    for (int k = 0; k < 9; ++k) {
        float4 wv[RPT];
#pragma unroll
        for (int i = 0; i < RPT; ++i) {
            wv[i] = *(const float4*)(rp[i] + 32 * k);
            n2[i] += wv[i].x * wv[i].x + wv[i].y * wv[i].y +
                     wv[i].z * wv[i].z + wv[i].w * wv[i].w;
        }
#pragma unroll
        for (int a = 0; a < 8; ++a) {
            const float4 av = s_a[ai[a] * 75 + 8 * k + p];  // single-aspect, 8 addrs
#pragma unroll
            for (int i = 0; i < RPT; ++i) {
                acc[a][i] = fmaf(av.x, wv[i].x, fmaf(av.y, wv[i].y,
                            fmaf(av.z, wv[i].z, fmaf(av.w, wv[i].w, acc[a][i]))));
            }
        }
    }
    // tail: cols j = 72+p for p < 3 (exec-masked once)
    if (p < 3) {
        float4 wv[RPT];
#pragma unroll
        for (int i = 0; i < RPT; ++i) {
            wv[i] = *(const float4*)(rp[i] + 288);
            n2[i] += wv[i].x * wv[i].x + wv[i].y * wv[i].y +
                     wv[i].z * wv[i].z + wv[i].w * wv[i].w;
        }
#pragma unroll
        for (int a = 0; a < 8; ++a) {
            const float4 av = s_a[ai[a] * 75 + 72 + p];
#pragma unroll
            for (int i = 0; i < RPT; ++i) {
                acc[a][i] = fmaf(av.x, wv[i].x, fmaf(av.y, wv[i].y,
                            fmaf(av.z, wv[i].z, fmaf(av.w, wv[i].w, acc[a][i]))));
            }
        }
    }

    // reduce across the 8 E-lanes (xor 1,2,4 stays inside 8-lane group)
#pragma unroll
    for (int i = 0; i < RPT; ++i) {
        n2[i] += __shfl_xor(n2[i], 1);
        n2[i] += __shfl_xor(n2[i], 2);
        n2[i] += __shfl_xor(n2[i], 4);
    }
#pragma unroll
    for (int a = 0; a < 8; ++a)
#pragma unroll
        for (int i = 0; i < RPT; ++i) {
            acc[a][i] += __shfl_xor(acc[a][i], 1);
            acc[a][i] += __shfl_xor(acc[a][i], 2);
            acc[a][i] += __shfl_xor(acc[a][i], 4);
        }

    // per-wave partial max over its aspects -> s_pm[row][wave]
    if (p == 0) {
#pragma unroll
        for (int i = 0; i < RPT; ++i) {
            const float invx = 1.f / fmaxf(sqrtf(n2[i]), COS_EPS_F);
            float pm = 0.f;
            for (int a = 0; a < cw; ++a) {
                const float cosv = acc[a][i] * s_scale[abase + a] * invx;
                pm = fmaxf(pm, (cosv > WORD_THRES) ? cosv * s_aw[abase + a] : 0.f);
            }
            s_pm[(s * RPT + i) * 4 + w] = pm;
        }
    }
    __syncthreads();

    if (t < ROWS_PER_BLOCK) {
        const int v = blockIdx.x * ROWS_PER_BLOCK + t;
        if (v < VV) {
            const float4 q = *(const float4*)(s_pm + t * 4);
            cent[v] = fmaxf(fmaxf(q.x, q.y), fmaxf(q.z, q.w));
        }
    }
}

// ---------------------------------------------------------------------------
// Kernel 2: one block per batch row. 3 barriers. Sparse z over the ~2-8
// active positions (a_l == 0 exactly for masked positions).
// ---------------------------------------------------------------------------
__global__ void __launch_bounds__(256) row_kernel(
    const int* __restrict__ inputs,   // [B, L]
    const float* __restrict__ w_emb,  // [V, E]
    const float* __restrict__ cent,   // [V]
    float* __restrict__ out)          // enc_out [B,E] | a [B,L] | cs [B]
{
    const int b = blockIdx.x;
    const int t = threadIdx.x;          // == l
    const int wid = t >> 6, lane = t & 63;

    __shared__ float pA[4], pB[4], pC[4], pD[4];
    __shared__ int s_nact;
    __shared__ int s_act_id[LL];
    __shared__ float s_act_w[LL];

    const int id = inputs[b * LL + t];
    const float c = cent[id];
    const float score = (c > 0.f) ? c : NEG_INF_F;
    const float cnt = (id != 0) ? 1.f : 0.f;
    if (t == 0) s_nact = 0;

    // fused sum(c) / sum(cnt) / max(score) in one shuffle pass
    float s1 = c, s2 = cnt, s3 = score;
#pragma unroll
    for (int o = 32; o > 0; o >>= 1) {
        s1 += __shfl_down(s1, o);
        s2 += __shfl_down(s2, o);
        s3 = fmaxf(s3, __shfl_down(s3, o));
    }
    if (lane == 0) { pA[wid] = s1; pB[wid] = s2; pC[wid] = s3; }
    __syncthreads();

    const float sum_c = pA[0] + pA[1] + pA[2] + pA[3];
    const float len   = pB[0] + pB[1] + pB[2] + pB[3];
    const float mx    = fmaxf(fmaxf(pC[0], pC[1]), fmaxf(pC[2], pC[3]));

    const float p = expf(score - mx);   // expf(-1e9)==0; all-masked row -> p=1
    float s4 = p;
#pragma unroll
    for (int o = 32; o > 0; o >>= 1) s4 += __shfl_down(s4, o);
    if (lane == 0) pD[wid] = s4;
    __syncthreads();
    const float sum_p = pD[0] + pD[1] + pD[2] + pD[3];

    const float a_l = p / sum_p;
    const float cs = sum_c / (len + 1e-5f);
    const float gate = (cs > 1e-4f) ? 1.f : 0.f;

    out[BB * EE + b * LL + t] = a_l;            // attention
    if (t == 0) out[BB * EE + BB * LL + b] = cs;

    if (score > -1e8f) {                         // active <=> cent > 0
        const int i = atomicAdd(&s_nact, 1);
        s_act_id[i] = id;
        s_act_w[i] = a_l;
    }
    __syncthreads();
    const int n = s_nact;

    // z over active entries only; thread t<75 owns float4 column t
    if (t < EE / 4) {
        float4 acc = {0.f, 0.f, 0.f, 0.f};
        for (int i = 0; i < n; ++i) {
            const float wgt = s_act_w[i];
            const float4 rr = *(const float4*)(w_emb + (size_t)s_act_id[i] * EE + 4 * t);
            acc.x += wgt * rr.x; acc.y += wgt * rr.y;
            acc.z += wgt * rr.z; acc.w += wgt * rr.w;
        }
        acc.x *= gate; acc.y *= gate; acc.z *= gate; acc.w *= gate;
        *(float4*)(out + b * EE + 4 * t) = acc;
    }
}

// ---------------------------------------------------------------------------
extern "C" void kernel_launch(void* const* d_in, const int* in_sizes, int n_in,
                              void* d_out, int out_size, void* d_ws, size_t ws_size,
                              hipStream_t stream) {
    const int* inputs = (const int*)d_in[0];
    const float* w_emb = (const float*)d_in[1];
    const float* a_emb = (const float*)d_in[2];
    const float* a_weight = (const float*)d_in[3];
    float* out = (float*)d_out;
    float* cent = (float*)d_ws;  // 50000 floats = 200 KB scratch

    cent_kernel<<<(VV + ROWS_PER_BLOCK - 1) / ROWS_PER_BLOCK, 256, 0, stream>>>(
        w_emb, a_emb, a_weight, cent);
    row_kernel<<<BB, 256, 0, stream>>>(inputs, w_emb, cent, out);
}

// Round 7
// 234.378 us; speedup vs baseline: 2.5535x; 2.5535x over previous
//
#include <hip/hip_runtime.h>
#include <math.h>

#define BB 1024
#define LL 256
#define VV 50000
#define EE 300
#define AA 30
#define RPT 6                      // vocab rows per thread
#define ROWS_PER_BLOCK 48          // 8 slots * RPT
#define WORD_THRES 0.2f
#define COS_EPS_F 1e-8f
#define NEG_INF_F -1e9f

// ---------------------------------------------------------------------------
// Kernel 1: cent[v] = max_a ( (cos(a_emb[a], w_emb[v]) > thres ? cos : 0) * w[a] )
// R6 structure (aspect-split across waves: 8/8/7/7; lane = 8 E-lanes x 8 row
// slots; 6 rows/thread; single-aspect ds_read_b128 -> zero bank conflicts)
// with the R6 bug fixed: __launch_bounds__(256,2) instead of (256,4).
// R6's (256,4) forced a 64-VGPR allocation against ~95 live regs -> 1.5 GB
// of scratch spill traffic (WRITE_SIZE 896 MB). Natural allocation ~110.
// ---------------------------------------------------------------------------
__global__ void __launch_bounds__(256, 2) cent_kernel(
    const float* __restrict__ w_emb,     // [V, E]
    const float* __restrict__ a_emb,     // [A, E]
    const float* __restrict__ a_weight,  // [A]
    float* __restrict__ cent)            // [V]
{
    __shared__ float4 s_a[AA * 75];      // a-major: s_a[a*75 + j], 36000 B
    __shared__ float s_scale[AA];        // 1 / max(||a||, eps)
    __shared__ float s_aw[AA];
    __shared__ float s_pm[ROWS_PER_BLOCK * 4];  // per-row partial max per wave

    const int t = threadIdx.x;
    const int lane = t & 63;
    const int w = t >> 6;            // wave id 0..3
    const int p = lane & 7;          // E-lane: float4 col j = 8k + p
    const int s = lane >> 3;         // row slot 0..7

    const float4* __restrict__ a4 = (const float4*)a_emb;   // [A][75]

    // stage a_emb -> LDS (coalesced copy)
    for (int i = t; i < AA * 75; i += 256) s_a[i] = a4[i];
    __syncthreads();

    // aspect norms from LDS: 8 lanes per aspect (in-wave groups, thr 0..239)
    {
        const int a = t >> 3, j = t & 7;
        if (a < AA) {
            float n2a = 0.f;
            for (int c = j; c < 75; c += 8) {
                const float4 x = s_a[a * 75 + c];
                n2a += x.x * x.x + x.y * x.y + x.z * x.z + x.w * x.w;
            }
            n2a += __shfl_xor(n2a, 1);
            n2a += __shfl_xor(n2a, 2);
            n2a += __shfl_xor(n2a, 4);
            if (j == 0) {
                s_scale[a] = 1.f / fmaxf(sqrtf(n2a), COS_EPS_F);
                s_aw[a] = a_weight[a];
            }
        }
    }
    __syncthreads();

    // wave's aspect range: 8,8,7,7 -> bases 0,8,16,23 (wave-uniform -> SGPR)
    const int abase = __builtin_amdgcn_readfirstlane((w < 3) ? w * 8 : 23);
    const int cw    = __builtin_amdgcn_readfirstlane((w < 2) ? 8 : 7);
    int ai[8];
#pragma unroll
    for (int a = 0; a < 8; ++a) ai[a] = abase + ((a < cw) ? a : cw - 1);

    // row pointers (clamped for tail block), pre-offset by this lane's p
    const int vbase = blockIdx.x * ROWS_PER_BLOCK + s * RPT;
    const float* __restrict__ rp[RPT];
#pragma unroll
    for (int i = 0; i < RPT; ++i) {
        const int v = vbase + i;
        rp[i] = w_emb + (size_t)((v < VV) ? v : 0) * EE + 4 * p;
    }

    float acc[8][RPT];
#pragma unroll
    for (int a = 0; a < 8; ++a)
#pragma unroll
        for (int i = 0; i < RPT; ++i) acc[a][i] = 0.f;
    float n2[RPT] = {0.f, 0.f, 0.f, 0.f, 0.f, 0.f};

    // main loop: k = 0..8, col j = 8k+p <= 71, branch-free
#pragma unroll
    for (int k = 0; k < 9; ++k) {
        float4 wv[RPT];
#pragma unroll
        for (int i = 0; i < RPT; ++i) {
            wv[i] = *(const float4*)(rp[i] + 32 * k);
            n2[i] += wv[i].x * wv[i].x + wv[i].y * wv[i].y +
                     wv[i].z * wv[i].z + wv[i].w * wv[i].w;
        }
#pragma unroll
        for (int a = 0; a < 8; ++a) {
            const float4 av = s_a[ai[a] * 75 + 8 * k + p];  // single-aspect, 8 addrs
#pragma unroll
            for (int i = 0; i < RPT; ++i) {
                acc[a][i] = fmaf(av.x, wv[i].x, fmaf(av.y, wv[i].y,
                            fmaf(av.z, wv[i].z, fmaf(av.w, wv[i].w, acc[a][i]))));
            }
        }
    }
    // tail: cols j = 72+p for p < 3 (exec-masked once)
    if (p < 3) {
        float4 wv[RPT];
#pragma unroll
        for (int i = 0; i < RPT; ++i) {
            wv[i] = *(const float4*)(rp[i] + 288);
            n2[i] += wv[i].x * wv[i].x + wv[i].y * wv[i].y +
                     wv[i].z * wv[i].z + wv[i].w * wv[i].w;
        }
#pragma unroll
        for (int a = 0; a < 8; ++a) {
            const float4 av = s_a[ai[a] * 75 + 72 + p];
#pragma unroll
            for (int i = 0; i < RPT; ++i) {
                acc[a][i] = fmaf(av.x, wv[i].x, fmaf(av.y, wv[i].y,
                            fmaf(av.z, wv[i].z, fmaf(av.w, wv[i].w, acc[a][i]))));
            }
        }
    }

    // reduce across the 8 E-lanes (xor 1,2,4 stays inside 8-lane group)
#pragma unroll
    for (int i = 0; i < RPT; ++i) {
        n2[i] += __shfl_xor(n2[i], 1);
        n2[i] += __shfl_xor(n2[i], 2);
        n2[i] += __shfl_xor(n2[i], 4);
    }
#pragma unroll
    for (int a = 0; a < 8; ++a)
#pragma unroll
        for (int i = 0; i < RPT; ++i) {
            acc[a][i] += __shfl_xor(acc[a][i], 1);
            acc[a][i] += __shfl_xor(acc[a][i], 2);
            acc[a][i] += __shfl_xor(acc[a][i], 4);
        }

    // per-wave partial max over its aspects -> s_pm[row][wave]
    if (p == 0) {
#pragma unroll
        for (int i = 0; i < RPT; ++i) {
            const float invx = 1.f / fmaxf(sqrtf(n2[i]), COS_EPS_F);
            float pm = 0.f;
            for (int a = 0; a < cw; ++a) {
                const float cosv = acc[a][i] * s_scale[abase + a] * invx;
                pm = fmaxf(pm, (cosv > WORD_THRES) ? cosv * s_aw[abase + a] : 0.f);
            }
            s_pm[(s * RPT + i) * 4 + w] = pm;
        }
    }
    __syncthreads();

    if (t < ROWS_PER_BLOCK) {
        const int v = blockIdx.x * ROWS_PER_BLOCK + t;
        if (v < VV) {
            const float4 q = *(const float4*)(s_pm + t * 4);
            cent[v] = fmaxf(fmaxf(q.x, q.y), fmaxf(q.z, q.w));
        }
    }
}

// ---------------------------------------------------------------------------
// Kernel 2: one block per batch row. 3 barriers. Sparse z over the ~2-8
// active positions (a_l == 0 exactly for masked positions).
// ---------------------------------------------------------------------------
__global__ void __launch_bounds__(256) row_kernel(
    const int* __restrict__ inputs,   // [B, L]
    const float* __restrict__ w_emb,  // [V, E]
    const float* __restrict__ cent,   // [V]
    float* __restrict__ out)          // enc_out [B,E] | a [B,L] | cs [B]
{
    const int b = blockIdx.x;
    const int t = threadIdx.x;          // == l
    const int wid = t >> 6, lane = t & 63;

    __shared__ float pA[4], pB[4], pC[4], pD[4];
    __shared__ int s_nact;
    __shared__ int s_act_id[LL];
    __shared__ float s_act_w[LL];

    const int id = inputs[b * LL + t];
    const float c = cent[id];
    const float score = (c > 0.f) ? c : NEG_INF_F;
    const float cnt = (id != 0) ? 1.f : 0.f;
    if (t == 0) s_nact = 0;

    // fused sum(c) / sum(cnt) / max(score) in one shuffle pass
    float s1 = c, s2 = cnt, s3 = score;
#pragma unroll
    for (int o = 32; o > 0; o >>= 1) {
        s1 += __shfl_down(s1, o);
        s2 += __shfl_down(s2, o);
        s3 = fmaxf(s3, __shfl_down(s3, o));
    }
    if (lane == 0) { pA[wid] = s1; pB[wid] = s2; pC[wid] = s3; }
    __syncthreads();

    const float sum_c = pA[0] + pA[1] + pA[2] + pA[3];
    const float len   = pB[0] + pB[1] + pB[2] + pB[3];
    const float mx    = fmaxf(fmaxf(pC[0], pC[1]), fmaxf(pC[2], pC[3]));

    const float p = expf(score - mx);   // expf(-1e9)==0; all-masked row -> p=1
    float s4 = p;
#pragma unroll
    for (int o = 32; o > 0; o >>= 1) s4 += __shfl_down(s4, o);
    if (lane == 0) pD[wid] = s4;
    __syncthreads();
    const float sum_p = pD[0] + pD[1] + pD[2] + pD[3];

    const float a_l = p / sum_p;
    const float cs = sum_c / (len + 1e-5f);
    const float gate = (cs > 1e-4f) ? 1.f : 0.f;

    out[BB * EE + b * LL + t] = a_l;            // attention
    if (t == 0) out[BB * EE + BB * LL + b] = cs;

    if (score > -1e8f) {                         // active <=> cent > 0
        const int i = atomicAdd(&s_nact, 1);
        s_act_id[i] = id;
        s_act_w[i] = a_l;
    }
    __syncthreads();
    const int n = s_nact;

    // z over active entries only; thread t<75 owns float4 column t
    if (t < EE / 4) {
        float4 acc = {0.f, 0.f, 0.f, 0.f};
        for (int i = 0; i < n; ++i) {
            const float wgt = s_act_w[i];
            const float4 rr = *(const float4*)(w_emb + (size_t)s_act_id[i] * EE + 4 * t);
            acc.x += wgt * rr.x; acc.y += wgt * rr.y;
            acc.z += wgt * rr.z; acc.w += wgt * rr.w;
        }
        acc.x *= gate; acc.y *= gate; acc.z *= gate; acc.w *= gate;
        *(float4*)(out + b * EE + 4 * t) = acc;
    }
}

// ---------------------------------------------------------------------------
extern "C" void kernel_launch(void* const* d_in, const int* in_sizes, int n_in,
                              void* d_out, int out_size, void* d_ws, size_t ws_size,
                              hipStream_t stream) {
    const int* inputs = (const int*)d_in[0];
    const float* w_emb = (const float*)d_in[1];
    const float* a_emb = (const float*)d_in[2];
    const float* a_weight = (const float*)d_in[3];
    float* out = (float*)d_out;
    float* cent = (float*)d_ws;  // 50000 floats = 200 KB scratch

    cent_kernel<<<(VV + ROWS_PER_BLOCK - 1) / ROWS_PER_BLOCK, 256, 0, stream>>>(
        w_emb, a_emb, a_weight, cent);
    row_kernel<<<BB, 256, 0, stream>>>(inputs, w_emb, cent, out);
}

// Round 8
// 152.501 us; speedup vs baseline: 3.9245x; 1.5369x over previous
//
#include <hip/hip_runtime.h>
#include <math.h>

#define BB 1024
#define LL 256
#define VV 50000
#define EE 300
#define AA 30
#define RPT 4                      // vocab rows per thread
#define ROWS_PER_BLOCK 32          // 8 slots * RPT
#define WORD_THRES 0.2f
#define COS_EPS_F 1e-8f
#define NEG_INF_F -1e9f

// ---------------------------------------------------------------------------
// Kernel 1: cent[v] = max_a ( (cos(a_emb[a], w_emb[v]) > thres ? cos : 0) * w[a] )
// Aspect-per-wave structure (validated R6/R7: zero LDS conflicts, 16 FMAs per
// ds_read_b128) with the spill fixed:
//  - no min-waves launch bound (R7: allocator pinned 128 VGPR + spilled 220 MB)
//  - RPT=4 (acc 32 + wv 16 regs, live ~85) -> natural alloc, no scratch
//  - aspect windows 0-7/8-15/16-23/22-29 (overlap 22-23 duplicated; max is
//    idempotent) -> no ai[] array, compile-time LDS offsets
// Grid 1563 blocks, LDS 36.4 KB -> 4 blocks/CU resident, ~16 waves/CU.
// ---------------------------------------------------------------------------
__global__ void __launch_bounds__(256) cent_kernel(
    const float* __restrict__ w_emb,     // [V, E]
    const float* __restrict__ a_emb,     // [A, E]
    const float* __restrict__ a_weight,  // [A]
    float* __restrict__ cent)            // [V]
{
    __shared__ float4 s_a[AA * 75];      // a-major: s_a[a*75 + j], 36000 B
    __shared__ float s_scale[AA];        // 1 / max(||a||, eps)
    __shared__ float s_aw[AA];
    __shared__ float s_pm[ROWS_PER_BLOCK * 4];  // per-row partial max per wave

    const int t = threadIdx.x;
    const int lane = t & 63;
    const int w = t >> 6;            // wave id 0..3
    const int p = lane & 7;          // E-lane: float4 col j = 8k + p
    const int s = lane >> 3;         // row slot 0..7

    const float4* __restrict__ a4 = (const float4*)a_emb;   // [A][75]

    // stage a_emb -> LDS (coalesced copy)
    for (int i = t; i < AA * 75; i += 256) s_a[i] = a4[i];
    __syncthreads();

    // aspect norms from LDS: 8 lanes per aspect (in-wave groups, thr 0..239)
    {
        const int a = t >> 3, j = t & 7;
        if (a < AA) {
            float n2a = 0.f;
            for (int c = j; c < 75; c += 8) {
                const float4 x = s_a[a * 75 + c];
                n2a += x.x * x.x + x.y * x.y + x.z * x.z + x.w * x.w;
            }
            n2a += __shfl_xor(n2a, 1);
            n2a += __shfl_xor(n2a, 2);
            n2a += __shfl_xor(n2a, 4);
            if (j == 0) {
                s_scale[a] = 1.f / fmaxf(sqrtf(n2a), COS_EPS_F);
                s_aw[a] = a_weight[a];
            }
        }
    }
    __syncthreads();

    // wave's aspect window: 0-7 / 8-15 / 16-23 / 22-29 (fixed 8 aspects)
    const int abase = __builtin_amdgcn_readfirstlane((w < 3) ? w * 8 : 22);
    const float4* __restrict__ sa = s_a + abase * 75;  // uniform wave base

    // row pointers (clamped for tail block), pre-offset by this lane's p
    const int vbase = blockIdx.x * ROWS_PER_BLOCK + s * RPT;
    const float* __restrict__ rp[RPT];
#pragma unroll
    for (int i = 0; i < RPT; ++i) {
        const int v = vbase + i;
        rp[i] = w_emb + (size_t)((v < VV) ? v : 0) * EE + 4 * p;
    }

    float acc[8][RPT];
#pragma unroll
    for (int a = 0; a < 8; ++a)
#pragma unroll
        for (int i = 0; i < RPT; ++i) acc[a][i] = 0.f;
    float n2[RPT] = {0.f, 0.f, 0.f, 0.f};

    // main loop: k = 0..8, col j = 8k+p <= 71
#pragma unroll
    for (int k = 0; k < 9; ++k) {
        float4 wv[RPT];
#pragma unroll
        for (int i = 0; i < RPT; ++i) {
            wv[i] = *(const float4*)(rp[i] + 32 * k);
            n2[i] += wv[i].x * wv[i].x + wv[i].y * wv[i].y +
                     wv[i].z * wv[i].z + wv[i].w * wv[i].w;
        }
#pragma unroll
        for (int a = 0; a < 8; ++a) {
            const float4 av = sa[a * 75 + 8 * k + p];  // single-aspect, 8 addrs
#pragma unroll
            for (int i = 0; i < RPT; ++i) {
                acc[a][i] = fmaf(av.x, wv[i].x, fmaf(av.y, wv[i].y,
                            fmaf(av.z, wv[i].z, fmaf(av.w, wv[i].w, acc[a][i]))));
            }
        }
    }
    // tail: cols j = 72+p for p < 3 (exec-masked once)
    if (p < 3) {
        float4 wv[RPT];
#pragma unroll
        for (int i = 0; i < RPT; ++i) {
            wv[i] = *(const float4*)(rp[i] + 288);
            n2[i] += wv[i].x * wv[i].x + wv[i].y * wv[i].y +
                     wv[i].z * wv[i].z + wv[i].w * wv[i].w;
        }
#pragma unroll
        for (int a = 0; a < 8; ++a) {
            const float4 av = sa[a * 75 + 72 + p];
#pragma unroll
            for (int i = 0; i < RPT; ++i) {
                acc[a][i] = fmaf(av.x, wv[i].x, fmaf(av.y, wv[i].y,
                            fmaf(av.z, wv[i].z, fmaf(av.w, wv[i].w, acc[a][i]))));
            }
        }
    }

    // reduce across the 8 E-lanes (xor 1,2,4 stays inside 8-lane group)
#pragma unroll
    for (int i = 0; i < RPT; ++i) {
        n2[i] += __shfl_xor(n2[i], 1);
        n2[i] += __shfl_xor(n2[i], 2);
        n2[i] += __shfl_xor(n2[i], 4);
    }
#pragma unroll
    for (int a = 0; a < 8; ++a)
#pragma unroll
        for (int i = 0; i < RPT; ++i) {
            acc[a][i] += __shfl_xor(acc[a][i], 1);
            acc[a][i] += __shfl_xor(acc[a][i], 2);
            acc[a][i] += __shfl_xor(acc[a][i], 4);
        }

    // per-wave partial max over its 8 aspects -> s_pm[row][wave]
    if (p == 0) {
#pragma unroll
        for (int i = 0; i < RPT; ++i) {
            const float invx = 1.f / fmaxf(sqrtf(n2[i]), COS_EPS_F);
            float pm = 0.f;
#pragma unroll
            for (int a = 0; a < 8; ++a) {
                const float cosv = acc[a][i] * s_scale[abase + a] * invx;
                pm = fmaxf(pm, (cosv > WORD_THRES) ? cosv * s_aw[abase + a] : 0.f);
            }
            s_pm[(s * RPT + i) * 4 + w] = pm;
        }
    }
    __syncthreads();

    if (t < ROWS_PER_BLOCK) {
        const int v = blockIdx.x * ROWS_PER_BLOCK + t;
        if (v < VV) {
            const float4 q = *(const float4*)(s_pm + t * 4);
            cent[v] = fmaxf(fmaxf(q.x, q.y), fmaxf(q.z, q.w));
        }
    }
}

// ---------------------------------------------------------------------------
// Kernel 2: one block per batch row. 3 barriers. Sparse z over the ~2-8
// active positions (a_l == 0 exactly for masked positions).
// ---------------------------------------------------------------------------
__global__ void __launch_bounds__(256) row_kernel(
    const int* __restrict__ inputs,   // [B, L]
    const float* __restrict__ w_emb,  // [V, E]
    const float* __restrict__ cent,   // [V]
    float* __restrict__ out)          // enc_out [B,E] | a [B,L] | cs [B]
{
    const int b = blockIdx.x;
    const int t = threadIdx.x;          // == l
    const int wid = t >> 6, lane = t & 63;

    __shared__ float pA[4], pB[4], pC[4], pD[4];
    __shared__ int s_nact;
    __shared__ int s_act_id[LL];
    __shared__ float s_act_w[LL];

    const int id = inputs[b * LL + t];
    const float c = cent[id];
    const float score = (c > 0.f) ? c : NEG_INF_F;
    const float cnt = (id != 0) ? 1.f : 0.f;
    if (t == 0) s_nact = 0;

    // fused sum(c) / sum(cnt) / max(score) in one shuffle pass
    float s1 = c, s2 = cnt, s3 = score;
#pragma unroll
    for (int o = 32; o > 0; o >>= 1) {
        s1 += __shfl_down(s1, o);
        s2 += __shfl_down(s2, o);
        s3 = fmaxf(s3, __shfl_down(s3, o));
    }
    if (lane == 0) { pA[wid] = s1; pB[wid] = s2; pC[wid] = s3; }
    __syncthreads();

    const float sum_c = pA[0] + pA[1] + pA[2] + pA[3];
    const float len   = pB[0] + pB[1] + pB[2] + pB[3];
    const float mx    = fmaxf(fmaxf(pC[0], pC[1]), fmaxf(pC[2], pC[3]));

    const float p = expf(score - mx);   // expf(-1e9)==0; all-masked row -> p=1
    float s4 = p;
#pragma unroll
    for (int o = 32; o > 0; o >>= 1) s4 += __shfl_down(s4, o);
    if (lane == 0) pD[wid] = s4;
    __syncthreads();
    const float sum_p = pD[0] + pD[1] + pD[2] + pD[3];

    const float a_l = p / sum_p;
    const float cs = sum_c / (len + 1e-5f);
    const float gate = (cs > 1e-4f) ? 1.f : 0.f;

    out[BB * EE + b * LL + t] = a_l;            // attention
    if (t == 0) out[BB * EE + BB * LL + b] = cs;

    if (score > -1e8f) {                         // active <=> cent > 0
        const int i = atomicAdd(&s_nact, 1);
        s_act_id[i] = id;
        s_act_w[i] = a_l;
    }
    __syncthreads();
    const int n = s_nact;

    // z over active entries only; thread t<75 owns float4 column t
    if (t < EE / 4) {
        float4 acc = {0.f, 0.f, 0.f, 0.f};
        for (int i = 0; i < n; ++i) {
            const float wgt = s_act_w[i];
            const float4 rr = *(const float4*)(w_emb + (size_t)s_act_id[i] * EE + 4 * t);
            acc.x += wgt * rr.x; acc.y += wgt * rr.y;
            acc.z += wgt * rr.z; acc.w += wgt * rr.w;
        }
        acc.x *= gate; acc.y *= gate; acc.z *= gate; acc.w *= gate;
        *(float4*)(out + b * EE + 4 * t) = acc;
    }
}

// ---------------------------------------------------------------------------
extern "C" void kernel_launch(void* const* d_in, const int* in_sizes, int n_in,
                              void* d_out, int out_size, void* d_ws, size_t ws_size,
                              hipStream_t stream) {
    const int* inputs = (const int*)d_in[0];
    const float* w_emb = (const float*)d_in[1];
    const float* a_emb = (const float*)d_in[2];
    const float* a_weight = (const float*)d_in[3];
    float* out = (float*)d_out;
    float* cent = (float*)d_ws;  // 50000 floats = 200 KB scratch

    cent_kernel<<<(VV + ROWS_PER_BLOCK - 1) / ROWS_PER_BLOCK, 256, 0, stream>>>(
        w_emb, a_emb, a_weight, cent);
    row_kernel<<<BB, 256, 0, stream>>>(inputs, w_emb, cent, out);
}

// Round 9
// 146.681 us; speedup vs baseline: 4.0802x; 1.0397x over previous
//
#include <hip/hip_runtime.h>
#include <math.h>

#define BB 1024
#define LL 256
#define VV 50000
#define EE 300
#define AA 30
#define RPT 4                      // vocab rows per thread per tile
#define TILE_ROWS 32               // 8 slots * RPT
#define NTILES ((VV + TILE_ROWS - 1) / TILE_ROWS)   // 1563
#define CENT_BLOCKS 512
#define WORD_THRES 0.2f
#define COS_EPS_F 1e-8f
#define NEG_INF_F -1e9f

// ---------------------------------------------------------------------------
// Kernel 1: cent[v] = max_a ( (cos(a_emb[a], w_emb[v]) > thres ? cos : 0) * w[a] )
// PERSISTENT TILES: R4/R5/R8 showed time scales with block count at constant
// work (391->45us, 782->46us, 1563->80us): the 36KB-staging prologue dominates.
// Grid = 512 blocks (2/CU resident), each stages a_emb ONCE and grid-strides
// over 1563 row-tiles (~3 each) using the validated R8 inner loop:
// aspect-per-wave (0-7/8-15/16-23/22-29, max idempotent on the overlap),
// single-aspect ds_read_b128 -> zero bank conflicts, 16 FMAs per LDS read,
// no launch-bound min-waves (R6/R7: it forces spill-to-fit).
// ---------------------------------------------------------------------------
__global__ void __launch_bounds__(256) cent_kernel(
    const float* __restrict__ w_emb,     // [V, E]
    const float* __restrict__ a_emb,     // [A, E]
    const float* __restrict__ a_weight,  // [A]
    float* __restrict__ cent)            // [V]
{
    __shared__ float4 s_a[AA * 75];      // a-major: s_a[a*75 + j], 36000 B
    __shared__ float s_scale[AA];        // 1 / max(||a||, eps)
    __shared__ float s_aw[AA];
    __shared__ float s_pm[TILE_ROWS * 4];  // per-row partial max per wave

    const int t = threadIdx.x;
    const int lane = t & 63;
    const int w = t >> 6;            // wave id 0..3
    const int p = lane & 7;          // E-lane: float4 col j = 8k + p
    const int s = lane >> 3;         // row slot 0..7

    const float4* __restrict__ a4 = (const float4*)a_emb;   // [A][75]

    // ---- one-time prologue: stage a_emb -> LDS, compute aspect norms ----
    for (int i = t; i < AA * 75; i += 256) s_a[i] = a4[i];
    __syncthreads();
    {
        const int a = t >> 3, j = t & 7;
        if (a < AA) {
            float n2a = 0.f;
            for (int c = j; c < 75; c += 8) {
                const float4 x = s_a[a * 75 + c];
                n2a += x.x * x.x + x.y * x.y + x.z * x.z + x.w * x.w;
            }
            n2a += __shfl_xor(n2a, 1);
            n2a += __shfl_xor(n2a, 2);
            n2a += __shfl_xor(n2a, 4);
            if (j == 0) {
                s_scale[a] = 1.f / fmaxf(sqrtf(n2a), COS_EPS_F);
                s_aw[a] = a_weight[a];
            }
        }
    }
    __syncthreads();

    // wave's aspect window: 0-7 / 8-15 / 16-23 / 22-29 (fixed 8 aspects)
    const int abase = __builtin_amdgcn_readfirstlane((w < 3) ? w * 8 : 22);
    const float4* __restrict__ sa = s_a + abase * 75;  // uniform wave base

    // ---- persistent tile loop ----
    for (int tile = blockIdx.x; tile < NTILES; tile += CENT_BLOCKS) {
        const int vbase = tile * TILE_ROWS + s * RPT;
        const float* __restrict__ rp[RPT];
#pragma unroll
        for (int i = 0; i < RPT; ++i) {
            const int v = vbase + i;
            rp[i] = w_emb + (size_t)((v < VV) ? v : 0) * EE + 4 * p;
        }

        float acc[8][RPT];
#pragma unroll
        for (int a = 0; a < 8; ++a)
#pragma unroll
            for (int i = 0; i < RPT; ++i) acc[a][i] = 0.f;
        float n2[RPT] = {0.f, 0.f, 0.f, 0.f};

        // main loop: k = 0..8, col j = 8k+p <= 71
#pragma unroll
        for (int k = 0; k < 9; ++k) {
            float4 wv[RPT];
#pragma unroll
            for (int i = 0; i < RPT; ++i) {
                wv[i] = *(const float4*)(rp[i] + 32 * k);
                n2[i] += wv[i].x * wv[i].x + wv[i].y * wv[i].y +
                         wv[i].z * wv[i].z + wv[i].w * wv[i].w;
            }
#pragma unroll
            for (int a = 0; a < 8; ++a) {
                const float4 av = sa[a * 75 + 8 * k + p];  // single-aspect
#pragma unroll
                for (int i = 0; i < RPT; ++i) {
                    acc[a][i] = fmaf(av.x, wv[i].x, fmaf(av.y, wv[i].y,
                                fmaf(av.z, wv[i].z, fmaf(av.w, wv[i].w, acc[a][i]))));
                }
            }
        }
        // tail: cols j = 72+p for p < 3 (exec-masked once)
        if (p < 3) {
            float4 wv[RPT];
#pragma unroll
            for (int i = 0; i < RPT; ++i) {
                wv[i] = *(const float4*)(rp[i] + 288);
                n2[i] += wv[i].x * wv[i].x + wv[i].y * wv[i].y +
                         wv[i].z * wv[i].z + wv[i].w * wv[i].w;
            }
#pragma unroll
            for (int a = 0; a < 8; ++a) {
                const float4 av = sa[a * 75 + 72 + p];
#pragma unroll
                for (int i = 0; i < RPT; ++i) {
                    acc[a][i] = fmaf(av.x, wv[i].x, fmaf(av.y, wv[i].y,
                                fmaf(av.z, wv[i].z, fmaf(av.w, wv[i].w, acc[a][i]))));
                }
            }
        }

        // reduce across the 8 E-lanes (xor 1,2,4 stays inside 8-lane group)
#pragma unroll
        for (int i = 0; i < RPT; ++i) {
            n2[i] += __shfl_xor(n2[i], 1);
            n2[i] += __shfl_xor(n2[i], 2);
            n2[i] += __shfl_xor(n2[i], 4);
        }
#pragma unroll
        for (int a = 0; a < 8; ++a)
#pragma unroll
            for (int i = 0; i < RPT; ++i) {
                acc[a][i] += __shfl_xor(acc[a][i], 1);
                acc[a][i] += __shfl_xor(acc[a][i], 2);
                acc[a][i] += __shfl_xor(acc[a][i], 4);
            }

        // per-wave partial max over its 8 aspects -> s_pm[row][wave]
        if (p == 0) {
#pragma unroll
            for (int i = 0; i < RPT; ++i) {
                const float invx = 1.f / fmaxf(sqrtf(n2[i]), COS_EPS_F);
                float pm = 0.f;
#pragma unroll
                for (int a = 0; a < 8; ++a) {
                    const float cosv = acc[a][i] * s_scale[abase + a] * invx;
                    pm = fmaxf(pm, (cosv > WORD_THRES) ? cosv * s_aw[abase + a] : 0.f);
                }
                s_pm[(s * RPT + i) * 4 + w] = pm;
            }
        }
        __syncthreads();

        if (t < TILE_ROWS) {
            const int v = tile * TILE_ROWS + t;
            if (v < VV) {
                const float4 q = *(const float4*)(s_pm + t * 4);
                cent[v] = fmaxf(fmaxf(q.x, q.y), fmaxf(q.z, q.w));
            }
        }
        __syncthreads();   // protect s_pm before next tile overwrites it
    }
}

// ---------------------------------------------------------------------------
// Kernel 2: one block per batch row. 3 barriers. Sparse z over the ~2-8
// active positions (a_l == 0 exactly for masked positions).
// ---------------------------------------------------------------------------
__global__ void __launch_bounds__(256) row_kernel(
    const int* __restrict__ inputs,   // [B, L]
    const float* __restrict__ w_emb,  // [V, E]
    const float* __restrict__ cent,   // [V]
    float* __restrict__ out)          // enc_out [B,E] | a [B,L] | cs [B]
{
    const int b = blockIdx.x;
    const int t = threadIdx.x;          // == l
    const int wid = t >> 6, lane = t & 63;

    __shared__ float pA[4], pB[4], pC[4], pD[4];
    __shared__ int s_nact;
    __shared__ int s_act_id[LL];
    __shared__ float s_act_w[LL];

    const int id = inputs[b * LL + t];
    const float c = cent[id];
    const float score = (c > 0.f) ? c : NEG_INF_F;
    const float cnt = (id != 0) ? 1.f : 0.f;
    if (t == 0) s_nact = 0;

    // fused sum(c) / sum(cnt) / max(score) in one shuffle pass
    float s1 = c, s2 = cnt, s3 = score;
#pragma unroll
    for (int o = 32; o > 0; o >>= 1) {
        s1 += __shfl_down(s1, o);
        s2 += __shfl_down(s2, o);
        s3 = fmaxf(s3, __shfl_down(s3, o));
    }
    if (lane == 0) { pA[wid] = s1; pB[wid] = s2; pC[wid] = s3; }
    __syncthreads();

    const float sum_c = pA[0] + pA[1] + pA[2] + pA[3];
    const float len   = pB[0] + pB[1] + pB[2] + pB[3];
    const float mx    = fmaxf(fmaxf(pC[0], pC[1]), fmaxf(pC[2], pC[3]));

    const float p = expf(score - mx);   // expf(-1e9)==0; all-masked row -> p=1
    float s4 = p;
#pragma unroll
    for (int o = 32; o > 0; o >>= 1) s4 += __shfl_down(s4, o);
    if (lane == 0) pD[wid] = s4;
    __syncthreads();
    const float sum_p = pD[0] + pD[1] + pD[2] + pD[3];

    const float a_l = p / sum_p;
    const float cs = sum_c / (len + 1e-5f);
    const float gate = (cs > 1e-4f) ? 1.f : 0.f;

    out[BB * EE + b * LL + t] = a_l;            // attention
    if (t == 0) out[BB * EE + BB * LL + b] = cs;

    if (score > -1e8f) {                         // active <=> cent > 0
        const int i = atomicAdd(&s_nact, 1);
        s_act_id[i] = id;
        s_act_w[i] = a_l;
    }
    __syncthreads();
    const int n = s_nact;

    // z over active entries only; thread t<75 owns float4 column t
    if (t < EE / 4) {
        float4 acc = {0.f, 0.f, 0.f, 0.f};
        for (int i = 0; i < n; ++i) {
            const float wgt = s_act_w[i];
            const float4 rr = *(const float4*)(w_emb + (size_t)s_act_id[i] * EE + 4 * t);
            acc.x += wgt * rr.x; acc.y += wgt * rr.y;
            acc.z += wgt * rr.z; acc.w += wgt * rr.w;
        }
        acc.x *= gate; acc.y *= gate; acc.z *= gate; acc.w *= gate;
        *(float4*)(out + b * EE + 4 * t) = acc;
    }
}

// ---------------------------------------------------------------------------
extern "C" void kernel_launch(void* const* d_in, const int* in_sizes, int n_in,
                              void* d_out, int out_size, void* d_ws, size_t ws_size,
                              hipStream_t stream) {
    const int* inputs = (const int*)d_in[0];
    const float* w_emb = (const float*)d_in[1];
    const float* a_emb = (const float*)d_in[2];
    const float* a_weight = (const float*)d_in[3];
    float* out = (float*)d_out;
    float* cent = (float*)d_ws;  // 50000 floats = 200 KB scratch

    cent_kernel<<<CENT_BLOCKS, 256, 0, stream>>>(w_emb, a_emb, a_weight, cent);
    row_kernel<<<BB, 256, 0, stream>>>(inputs, w_emb, cent, out);
}